// Round 1
// 202.861 us; speedup vs baseline: 1.2331x; 1.2331x over previous
//
#include <hip/hip_runtime.h>
#include <stdint.h>

// ---------------------------------------------------------------------------
// Binarized QAT CNN forward (R15 = R14 + LDS-alias occupancy + prep rewrite).
//   - k_forward: p4 aliases a1 (a1 dead after phase 2, p4 written phase 3)
//     -> RIMG 23936->20032, LDS 47952->40144 B -> 4 blocks/CU (was 3).
//     clamp+1 folded into acc init (acc0 = 1 - rs), epilogue = med3(acc,0,2).
//     Scale read = max over 32 atomic slots.
//   - k_prep_max: conv1-max now 2 images/block (4096 blocks), float4 staging,
//     forward-identical pk-fma chains (i ascending, LDS-staged weights ->
//     bit-identical h values); atomicMax spread over ws[0..31].
//
// HARNESS RULE (R12): hipLaunchCooperativeKernel silently fails under graph
// capture here. Two plain dispatches are the minimum; do not retry coop.
// RACE RULE (R8/R9, confirmed R10): the wsmax line (d_ws bytes 0..255) is
// touched ONLY by signed atomicMax (0xAA poison is negative -> loses, so no
// zeroing store exists anywhere); all prep plain-stores live at byte >= 256.
// Slots 0..31 all atomic-only; untouched slots stay poison (negative float,
// loses the fmax reduce in k_forward).
// NUMERICS RULE (R8): conv1 must keep the exact pk-fma form (h += w1t2*s,
// i ascending, LDS-staged weights) in BOTH kernels — scalar-chain rewrites
// flip boundary decisions.
// NOTE: plain __launch_bounds__(256) — a min-waves arg caps arch VGPRs and
// spills ~50 dw/thread (R4: 426 MB scratch writes). Do not re-add it.
//
// MFMA i8 16x16x64 lane mapping (gfx950): A: lane l holds A[m=l&15][k=16q+j];
// B: B[k=16q+j][n=l&15]; D reg r: row=(l>>4)*4+r, col=l&15. A=weights =>
// A-row oc = col; lane's 4 D values = 4 consecutive channels of one pixel.
// K=144 padded to 192 by zeroing the WEIGHT fragment for k-blocks 9..11.
//
// d_ws layout (dwords): [0..31] wsmax slots (atomic-only line) |
//   [64..73] badj f32[10] | [80..95] rs2 | [96..127] rs3 | [128..703] w2m |
//   [704..1855] w3m | [1856..11535] sw   (total 46144 B)
// ---------------------------------------------------------------------------

typedef int int4v __attribute__((ext_vector_type(4)));
typedef float f2 __attribute__((ext_vector_type(2)));

__device__ __forceinline__ int4v mfma_i8(int4v a, int4v b, int4v c) {
  return __builtin_amdgcn_mfma_i32_16x16x64_i8(a, b, c, 0, 0, 0);
}

__device__ __forceinline__ int dot4(int a, int b, int c) {
#if __has_builtin(__builtin_amdgcn_sdot4)
  return __builtin_amdgcn_sdot4(a, b, c, false);
#else
  int r = c;
  r += (int)(int8_t)(a)       * (int)(int8_t)(b);
  r += (int)(int8_t)(a >> 8)  * (int)(int8_t)(b >> 8);
  r += (int)(int8_t)(a >> 16) * (int)(int8_t)(b >> 16);
  r += (int)(int8_t)(a >> 24) * (int)(int8_t)(b >> 24);
  return r;
#endif
}

// Pack low bytes of r0..r3 into one dword: [r0b0|r1b0|r2b0|r3b0].
__device__ __forceinline__ int pack4(int r0, int r1, int r2, int r3) {
  const int t0 = __builtin_amdgcn_perm(r1, r0, 0x00000400);
  const int t1 = __builtin_amdgcn_perm(r3, r2, 0x00000400);
  return __builtin_amdgcn_perm(t1, t0, 0x05040100);
}

// med3(v,0,2): acc init already carries the +1, so this is the whole epilogue.
__device__ __forceinline__ int cl02(int v) {
  v = (v > 0) ? v : 0;
  v = (v < 2) ? v : 2;
  return v;
}

__device__ __forceinline__ int sgn_pack_byte(float v) {
  return (v > 0.f) - (v < 0.f);
}

// Dispatch 1 -- merged conv1-max + prep.
// Blocks 0..NMAX-1: conv1-max over 2 images (forward-identical fma chains);
//   ws[0..31] touched ONLY by signed atomicMax (slot = blockIdx & 31).
// Blocks NMAX..NMAX+9: badj[j] (pb 1,2 also rs2/rs3). NMAX+10..NMAX+55: packing.
__global__ __launch_bounds__(256) void k_prep_max(
    const float* __restrict__ x, const float* __restrict__ w1,
    const float* __restrict__ w2, const float* __restrict__ w3,
    const float* __restrict__ wfc, const float* __restrict__ bfc,
    int* __restrict__ ws, int B, int NMAX) {
  __shared__ __align__(16) float xs[1568];
  __shared__ __align__(8) float w1t[144];
  __shared__ float wred[4];
  __shared__ int part[4];

  const int tid = threadIdx.x;
  if ((int)blockIdx.x < NMAX) {
    const int img0 = blockIdx.x * 2;
    const bool has1 = (img0 + 1) < B;
    {
      const float4* x4a = (const float4*)(x + (size_t)img0 * 784);
      const float4* x4b = (const float4*)(x + (size_t)(img0 + (int)has1) * 784);
      for (int u = tid; u < 392; u += 256) {
        const int im = (u >= 196), i = im ? u - 196 : u;
        const float4 v = im ? x4b[i] : x4a[i];
        *(float4*)&xs[im * 784 + i * 4] = v;
      }
    }
    if (tid < 144) w1t[(tid % 9) * 16 + tid / 9] = w1[tid];
    __syncthreads();
    const f2* w1t2 = (const f2*)w1t;
    const float* xs0 = xs;
    const float* xs1 = xs + 784;
    float m = 0.f;
    for (int px = tid; px < 676; px += 256) {
      const int oy = px / 26, ox = px - oy * 26;
      float xw0[9], xw1[9];
#pragma unroll
      for (int r = 0; r < 3; ++r)
#pragma unroll
        for (int cc = 0; cc < 3; ++cc) {
          const int ix = (oy + r) * 28 + ox + cc;
          xw0[r * 3 + cc] = xs0[ix];
          xw1[r * 3 + cc] = xs1[ix];
        }
#pragma unroll
      for (int cw = 0; cw < 8; ++cw) {
        f2 h0 = {0.f, 0.f}, h1 = {0.f, 0.f};
#pragma unroll
        for (int i = 0; i < 9; ++i) {
          const f2 w = w1t2[i * 8 + cw];
          const f2 s0 = {xw0[i], xw0[i]};
          const f2 s1 = {xw1[i], xw1[i]};
          h0 += w * s0;
          h1 += w * s1;
        }
        m = fmaxf(m, fmaxf(fmaxf(fabsf(h0.x), fabsf(h0.y)),
                           fmaxf(fabsf(h1.x), fabsf(h1.y))));
      }
    }
#pragma unroll
    for (int off = 32; off; off >>= 1) m = fmaxf(m, __shfl_down(m, off, 64));
    if ((tid & 63) == 0) wred[tid >> 6] = m;
    __syncthreads();
    if (tid == 0) {
      const float mm = fmaxf(fmaxf(wred[0], wred[1]), fmaxf(wred[2], wred[3]));
      atomicMax(ws + ((int)blockIdx.x & 31), (int)__float_as_uint(mm));
    }
    return;
  }

  const int pb = blockIdx.x - NMAX;  // prep block id 0..55
  if (pb < 10) {
    const int j = pb;
    int s = 0;
    for (int i = tid; i < 3872; i += 256) {
      const float v = wfc[j * 3872 + i];
      s += (v > 0.f) - (v < 0.f);
    }
#pragma unroll
    for (int off = 32; off; off >>= 1) s += __shfl_down(s, off, 64);
    if ((tid & 63) == 0) part[tid >> 6] = s;
    __syncthreads();
    if (tid == 0) {
      const int rs = part[0] + part[1] + part[2] + part[3];
      ((float*)ws)[64 + j] = bfc[j] - (float)rs;  // badj @ dword 64 (byte 256)
    }
    if (pb == 1 && tid < 16) {  // rs2[oc] @ dword 80
      int s2 = 0;
      for (int i = 0; i < 144; ++i) s2 += sgn_pack_byte(w2[tid * 144 + i]);
      ws[80 + tid] = s2;
    }
    if (pb == 2 && tid < 32) {  // rs3[oc] @ dword 96
      int s3 = 0;
      for (int i = 0; i < 144; ++i) s3 += sgn_pack_byte(w3[tid * 144 + i]);
      ws[96 + tid] = s3;
    }
    return;
  }
  int* dst = ws + 128;
  const int widx = (pb - 10) * 256 + tid;
  if (widx < 576) {  // w2m: dword = oc*36 + wp*4 + icg
    const int oc = widx / 36, r = widx % 36, wp = r >> 2, icg = r & 3;
    unsigned wrd = 0;
#pragma unroll
    for (int b = 0; b < 4; ++b) {
      const float v = w2[(oc * 16 + icg * 4 + b) * 9 + wp];
      wrd |= ((unsigned)(uint8_t)(int8_t)sgn_pack_byte(v)) << (8 * b);
    }
    dst[widx] = (int)wrd;
  } else if (widx < 1728) {  // w3m
    const int t = widx - 576;
    const int oc = t / 36, r = t % 36, wp = r >> 2, icg = r & 3;
    unsigned wrd = 0;
#pragma unroll
    for (int b = 0; b < 4; ++b) {
      const float v = w3[(oc * 16 + icg * 4 + b) * 9 + wp];
      wrd |= ((unsigned)(uint8_t)(int8_t)sgn_pack_byte(v)) << (8 * b);
    }
    dst[widx] = (int)wrd;
  } else if (widx < 11408) {  // sw: dword = j*968 + pos*8 + cg
    const int t = widx - 1728;
    const int j = t / 968, r = t % 968, pos = r >> 3, cg = r & 7;
    unsigned wrd = 0;
#pragma unroll
    for (int b = 0; b < 4; ++b) {
      const float v = wfc[j * 3872 + (cg * 4 + b) * 121 + pos];
      wrd |= ((unsigned)(uint8_t)(int8_t)sgn_pack_byte(v)) << (8 * b);
    }
    dst[widx] = (int)wrd;
  }
}

// ---------------------------------------------------------------------------
// Dispatch 2 -- k_forward: 2 images per block. LDS 40144 B -> 4 blocks/CU.
// Per-image region (stride RIMG=20032):
//   a1 @0 (10816 B; p4 [968 dw = 3872 B] ALIASES a1 head — a1 dead after
//   phase 2, p4 written phase 3) | h2 @10816 (9216 B; xs [3136 B] aliases;
//   w1t @13952 inside img0's h2 tail). out_acc @40064. Reads d_ws only.
// ---------------------------------------------------------------------------
__global__ __launch_bounds__(256) void k_forward(
    const float* __restrict__ x, const float* __restrict__ w1,
    const int* __restrict__ wsd,  // d_ws base (dword-indexed)
    float* __restrict__ out, int B) {
  __shared__ __align__(16) char smem[40144];
  constexpr int RIMG = 20032;
  int* out_acc = (int*)(smem + 40064);  // [2][10]

  const int* wpack = wsd + 128;          // w2m | w3m (w3m at wpack+576)
  const int* sw = wsd + 1856;            // [10][968] dw
  const float* badj = (const float*)(wsd + 64);

  const int tid = threadIdx.x;
  const int img0 = blockIdx.x * 2;
  const bool has1 = (img0 + 1) < B;

  // Stage: x -> xs[img] via float4 (784 floats = 196 f4/img), w1t, out_acc.
  {
    const float4* x4a = (const float4*)(x + (size_t)img0 * 784);
    const float4* x4b = (const float4*)(x + (size_t)(img0 + (int)has1) * 784);
    for (int u = tid; u < 392; u += 256) {
      const int img = (u >= 196), i = img ? u - 196 : u;
      const float4 v = img ? x4b[i] : x4a[i];
      *(float4*)(smem + img * RIMG + 10816 + i * 16) = v;
    }
  }
  if (tid < 144) *(float*)(smem + 13952 + ((tid % 9) * 16 + tid / 9) * 4) = w1[tid];
  if (tid < 20) out_acc[tid] = 0;
  __syncthreads();

  // Phase 1: conv1 -> a1 = (s+1) in {0,1,2}. Both images per weight fetch.
  // Scale = max over the 32 atomic slots (poison slots are negative, lose).
  float mraw = __uint_as_float((unsigned)wsd[0]);
#pragma unroll
  for (int k = 1; k < 32; ++k) mraw = fmaxf(mraw, __uint_as_float((unsigned)wsd[k]));
  const float scale = mraw / 127.0f + 1e-8f;
  const float thr = 0.5f * scale;
  const f2* w1t2 = (const f2*)(smem + 13952);
  const float* xs0 = (const float*)(smem + 10816);
  const float* xs1 = (const float*)(smem + RIMG + 10816);
  for (int px = tid; px < 676; px += 256) {
    const int oy = px / 26, ox = px - oy * 26;
    float xw0[9], xw1[9];
#pragma unroll
    for (int r = 0; r < 3; ++r)
#pragma unroll
      for (int cc = 0; cc < 3; ++cc) {
        const int ix = (oy + r) * 28 + ox + cc;
        xw0[r * 3 + cc] = xs0[ix];
        xw1[r * 3 + cc] = xs1[ix];
      }
    unsigned wq0[4] = {0u, 0u, 0u, 0u}, wq1[4] = {0u, 0u, 0u, 0u};
#pragma unroll
    for (int cw = 0; cw < 8; ++cw) {
      f2 h0 = {0.f, 0.f}, h1 = {0.f, 0.f};
#pragma unroll
      for (int i = 0; i < 9; ++i) {
        const f2 w = w1t2[i * 8 + cw];
        const f2 s0 = {xw0[i], xw0[i]};
        const f2 s1 = {xw1[i], xw1[i]};
        h0 += w * s0;
        h1 += w * s1;
      }
      // (s+1): 0 iff h < -thr, 1 iff |h| <= thr, 2 iff h > thr.
      wq0[cw >> 1] |= ((unsigned)((h0.x >= -thr) + (h0.x > thr))) << (8 * ((2 * cw) & 3));
      wq0[cw >> 1] |= ((unsigned)((h0.y >= -thr) + (h0.y > thr))) << (8 * ((2 * cw + 1) & 3));
      wq1[cw >> 1] |= ((unsigned)((h1.x >= -thr) + (h1.x > thr))) << (8 * ((2 * cw) & 3));
      wq1[cw >> 1] |= ((unsigned)((h1.y >= -thr) + (h1.y > thr))) << (8 * ((2 * cw + 1) & 3));
    }
    *(int4*)(smem + px * 16) =
        make_int4((int)wq0[0], (int)wq0[1], (int)wq0[2], (int)wq0[3]);
    *(int4*)(smem + RIMG + px * 16) =
        make_int4((int)wq1[0], (int)wq1[1], (int)wq1[2], (int)wq1[3]);
  }
  __syncthreads();

  // MFMA lane geometry.
  const int lane = tid & 63, wv = tid >> 6;
  const int col = lane & 15, quad = lane >> 4;
  int dAct2[3], dAct3[3];
#pragma unroll
  for (int t = 0; t < 3; ++t) {
    const int wp = t * 4 + quad;  // window pixel (k-block); wp>8 dead (A zeroed)
    dAct2[t] = ((wp / 3) * 26 + wp % 3) * 16;
    dAct3[t] = ((wp / 3) * 24 + wp % 3) * 16;
  }
  const bool kq0 = (quad == 0);  // t=2: only wp=8 is a real k-block

  // Phase 2: conv2. A=sign(w2) frags; acc init = 1 - rs2 (the +1 feeds cl02).
  {
    const int* wb = wpack + col * 36;  // A-row oc = col
    int4v WA[3];
    WA[0] = *(const int4v*)(wb + quad * 4);
    WA[1] = *(const int4v*)(wb + 16 + quad * 4);
    WA[2] = kq0 ? *(const int4v*)(wb + 32) : (int4v){0, 0, 0, 0};
    const int4v acc0 = (int4v){1, 1, 1, 1} - *(const int4v*)(wsd + 80 + quad * 4);
#pragma unroll
    for (int img = 0; img < 2; ++img) {
      const int8_t* a1b = (const int8_t*)(smem + img * RIMG);
      // incremental (oy,ox) over output pixel p = nt*16+col, nt += 4 (p += 64)
      int p0 = wv * 16 + col;
      int oy = p0 / 24, ox = p0 - oy * 24;
      const int8_t* abase = a1b + (oy * 26 + ox) * 16;
      int* h2p = (int*)(smem + img * RIMG + 10816 + p0 * 16 + quad * 4);
      for (int it = 0; it < 9; ++it) {
        int4v acc = acc0;
        acc = mfma_i8(WA[0], *(const int4v*)(abase + dAct2[0]), acc);
        acc = mfma_i8(WA[1], *(const int4v*)(abase + dAct2[1]), acc);
        acc = mfma_i8(WA[2], *(const int4v*)(abase + dAct2[2]), acc);
        *h2p = pack4(cl02(acc[0]), cl02(acc[1]), cl02(acc[2]), cl02(acc[3]));
        h2p += 256;         // +64 px * 16 B
        abase += 1088;      // (oy+=2, ox+=16)
        ox += 16;
        if (ox >= 24) { ox -= 24; abase += 32; }
      }
    }
  }
  __syncthreads();

  // Phase 3: conv3 + in-register pool. Pixels tiled pool-quad-major:
  // tile pt covers cells 4pt..4pt+3; lane col -> cell 4pt+(col>>2), sub col&3.
  // p4 (968 dw/img) is written into the a1 region (a1 dead after phase 2).
  {
    int4v WA[2][3];
    int4v ac0[2];
#pragma unroll
    for (int ot = 0; ot < 2; ++ot) {
      const int* wb = wpack + 576 + (ot * 16 + col) * 36;
      WA[ot][0] = *(const int4v*)(wb + quad * 4);
      WA[ot][1] = *(const int4v*)(wb + 16 + quad * 4);
      WA[ot][2] = kq0 ? *(const int4v*)(wb + 32) : (int4v){0, 0, 0, 0};
      ac0[ot] = (int4v){1, 1, 1, 1} - *(const int4v*)(wsd + 96 + ot * 16 + quad * 4);
    }
    const int sub = col & 3;
    const int sy = sub >> 1, sx = sub & 1;
    const int cell0 = wv * 4 + (col >> 2);
    const int cy0 = cell0 / 11, cx0 = cell0 - cy0 * 11;
    const int aoff0 = ((cy0 * 2 + sy) * 24 + cx0 * 2 + sx) * 16;
    const int pb0 = cell0 * 8 + quad;
    const int aoffcap = ((20 + sy) * 24 + 20 + sx) * 16;  // cell 120 clamp
    const int pbcap = 120 * 8 + quad;
    const bool wlane = (sub == 0);
#pragma unroll
    for (int img = 0; img < 2; ++img) {
      const int8_t* h2b = (const int8_t*)(smem + img * RIMG + 10816);
      int* p4 = (int*)(smem + img * RIMG);
      int aoff = aoff0, pb = pb0, cx = cx0;
      for (int pt = wv; pt < 31; pt += 4) {
        const int8_t* abase = h2b + ((aoff < aoffcap) ? aoff : aoffcap);
        const int pbu = (pb < pbcap) ? pb : pbcap;
        const int4v B0 = *(const int4v*)(abase + dAct3[0]);
        const int4v B1 = *(const int4v*)(abase + dAct3[1]);
        const int4v B2 = *(const int4v*)(abase + dAct3[2]);
#pragma unroll
        for (int ot = 0; ot < 2; ++ot) {
          int4v acc = ac0[ot];
          acc = mfma_i8(WA[ot][0], B0, acc);
          acc = mfma_i8(WA[ot][1], B1, acc);
          acc = mfma_i8(WA[ot][2], B2, acc);
          int s = pack4(cl02(acc[0]), cl02(acc[1]), cl02(acc[2]), cl02(acc[3]));
          // sum (s3+1) packed bytes across the lane nibble (cell's 2x2)
          s += __builtin_amdgcn_update_dpp(0, s, 0xB1, 0xF, 0xF, false);
          s += __builtin_amdgcn_update_dpp(0, s, 0x4E, 0xF, 0xF, false);
          if (wlane) p4[pbu + ot * 4] = s;
        }
        aoff += 928;  // cell += 16: (cy+=1, cx+=5)
        pb += 128;
        cx += 5;
        if (cx >= 11) { cx -= 11; aoff += 416; }
      }
    }
  }
  __syncthreads();

  // Phase 4: FC. acc = sum n*sw = 4*true + 4*rowsum(sw); badj corrects.
  for (int u = tid; u < 500; u += 256) {
    const int img = u / 250, r = u - img * 250;
    const int j = r / 25, k = r - j * 25;
    const int4* p44 = (const int4*)(smem + img * RIMG);
    int acc = 0;
    for (int pos = k; pos < 121; pos += 25) {
      const int4 pa = p44[pos * 2];
      const int4 pb = p44[pos * 2 + 1];
      const int* swr = sw + j * 968 + pos * 8;
      const int4 wa = *(const int4*)(swr);
      const int4 wbv = *(const int4*)(swr + 4);
      acc = dot4(pa.x, wa.x, acc);
      acc = dot4(pa.y, wa.y, acc);
      acc = dot4(pa.z, wa.z, acc);
      acc = dot4(pa.w, wa.w, acc);
      acc = dot4(pb.x, wbv.x, acc);
      acc = dot4(pb.y, wbv.y, acc);
      acc = dot4(pb.z, wbv.z, acc);
      acc = dot4(pb.w, wbv.w, acc);
    }
    atomicAdd(&out_acc[img * 10 + j], acc);
  }
  __syncthreads();
  if (tid < 20) {
    const int img = tid / 10, j = tid - img * 10;
    if (img == 0 || has1)
      out[(size_t)(img0 + img) * 10 + j] = 0.25f * (float)out_acc[tid] + badj[j];
  }
}

extern "C" void kernel_launch(void* const* d_in, const int* in_sizes, int n_in,
                              void* d_out, int out_size, void* d_ws, size_t ws_size,
                              hipStream_t stream) {
  const float* x   = (const float*)d_in[0];
  const float* w1  = (const float*)d_in[1];
  const float* w2  = (const float*)d_in[2];
  const float* w3  = (const float*)d_in[3];
  const float* wfc = (const float*)d_in[4];
  const float* bfc = (const float*)d_in[5];
  float* out = (float*)d_out;
  int* wsd = (int*)d_ws;
  const int B = in_sizes[0] / 784;
  const int NMAX = (B + 1) / 2;

  hipLaunchKernelGGL(k_prep_max, dim3(NMAX + 56), dim3(256), 0, stream,
                     x, w1, w2, w3, wfc, bfc, wsd, B, NMAX);
  hipLaunchKernelGGL(k_forward, dim3((B + 1) / 2), dim3(256), 0, stream, x, w1,
                     (const int*)wsd, out, B);
}

// Round 2
// 194.372 us; speedup vs baseline: 1.2869x; 1.0437x over previous
//
#include <hip/hip_runtime.h>
#include <stdint.h>

// ---------------------------------------------------------------------------
// Binarized QAT CNN forward (R16 = R15 + 1-img blocks + chunked phase1 + h2 pad).
//   - k_forward: 1 image/block (grid=B). LDS 20456 B -> 8 blocks/CU cap.
//     Phase 1 restructured: cw chunks of 2 with weights hoisted to regs
//     (chunk outer, px inner, wq kept in unrolled regs) -> phase-1 LDS
//     traffic ~4x lower; per-channel fma chains bit-identical.
//     h2 rows padded 24->25 px (400 B) -> phase-3 row reads bank-staggered.
//   - k_prep_max unchanged from R15. NOTE (R16 finding): total - forward is
//     ~96 us FIXED overhead (prep 4x-parallelism change moved it by only 2%);
//     prep compute is ~8 us. Do not optimize prep further.
//
// HARNESS RULE (R12): hipLaunchCooperativeKernel silently fails under graph
// capture here. Two plain dispatches are the minimum; do not retry coop.
// RACE RULE (R8/R9, confirmed R10): the wsmax line (d_ws bytes 0..255) is
// touched ONLY by signed atomicMax (0xAA poison is negative -> loses, so no
// zeroing store exists anywhere); all prep plain-stores live at byte >= 256.
// Slots 0..31 all atomic-only; untouched slots stay poison (negative float,
// loses the fmax reduce in k_forward).
// NUMERICS RULE (R8): conv1 must keep the exact pk-fma form (h += w*s,
// i ascending, LDS-staged weight values) in BOTH kernels — scalar-chain
// rewrites flip boundary decisions.
// NOTE: plain __launch_bounds__(256) — a min-waves arg caps arch VGPRs and
// spills ~50 dw/thread (R4: 426 MB scratch writes). Do not re-add it.
//
// MFMA i8 16x16x64 lane mapping (gfx950): A: lane l holds A[m=l&15][k=16q+j];
// B: B[k=16q+j][n=l&15]; D reg r: row=(l>>4)*4+r, col=l&15. A=weights =>
// A-row oc = col; lane's 4 D values = 4 consecutive channels of one pixel.
// K=144 padded to 192 by zeroing the WEIGHT fragment for k-blocks 9..11.
//
// d_ws layout (dwords): [0..31] wsmax slots (atomic-only line) |
//   [64..73] badj f32[10] | [80..95] rs2 | [96..127] rs3 | [128..703] w2m |
//   [704..1855] w3m | [1856..11535] sw   (total 46144 B)
// ---------------------------------------------------------------------------

typedef int int4v __attribute__((ext_vector_type(4)));
typedef float f2 __attribute__((ext_vector_type(2)));

__device__ __forceinline__ int4v mfma_i8(int4v a, int4v b, int4v c) {
  return __builtin_amdgcn_mfma_i32_16x16x64_i8(a, b, c, 0, 0, 0);
}

__device__ __forceinline__ int dot4(int a, int b, int c) {
#if __has_builtin(__builtin_amdgcn_sdot4)
  return __builtin_amdgcn_sdot4(a, b, c, false);
#else
  int r = c;
  r += (int)(int8_t)(a)       * (int)(int8_t)(b);
  r += (int)(int8_t)(a >> 8)  * (int)(int8_t)(b >> 8);
  r += (int)(int8_t)(a >> 16) * (int)(int8_t)(b >> 16);
  r += (int)(int8_t)(a >> 24) * (int)(int8_t)(b >> 24);
  return r;
#endif
}

// Pack low bytes of r0..r3 into one dword: [r0b0|r1b0|r2b0|r3b0].
__device__ __forceinline__ int pack4(int r0, int r1, int r2, int r3) {
  const int t0 = __builtin_amdgcn_perm(r1, r0, 0x00000400);
  const int t1 = __builtin_amdgcn_perm(r3, r2, 0x00000400);
  return __builtin_amdgcn_perm(t1, t0, 0x05040100);
}

// med3(v,0,2): acc init already carries the +1, so this is the whole epilogue.
__device__ __forceinline__ int cl02(int v) {
  v = (v > 0) ? v : 0;
  v = (v < 2) ? v : 2;
  return v;
}

__device__ __forceinline__ int sgn_pack_byte(float v) {
  return (v > 0.f) - (v < 0.f);
}

// Dispatch 1 -- merged conv1-max + prep (unchanged from R15).
__global__ __launch_bounds__(256) void k_prep_max(
    const float* __restrict__ x, const float* __restrict__ w1,
    const float* __restrict__ w2, const float* __restrict__ w3,
    const float* __restrict__ wfc, const float* __restrict__ bfc,
    int* __restrict__ ws, int B, int NMAX) {
  __shared__ __align__(16) float xs[1568];
  __shared__ __align__(8) float w1t[144];
  __shared__ float wred[4];
  __shared__ int part[4];

  const int tid = threadIdx.x;
  if ((int)blockIdx.x < NMAX) {
    const int img0 = blockIdx.x * 2;
    const bool has1 = (img0 + 1) < B;
    {
      const float4* x4a = (const float4*)(x + (size_t)img0 * 784);
      const float4* x4b = (const float4*)(x + (size_t)(img0 + (int)has1) * 784);
      for (int u = tid; u < 392; u += 256) {
        const int im = (u >= 196), i = im ? u - 196 : u;
        const float4 v = im ? x4b[i] : x4a[i];
        *(float4*)&xs[im * 784 + i * 4] = v;
      }
    }
    if (tid < 144) w1t[(tid % 9) * 16 + tid / 9] = w1[tid];
    __syncthreads();
    const f2* w1t2 = (const f2*)w1t;
    const float* xs0 = xs;
    const float* xs1 = xs + 784;
    float m = 0.f;
    for (int px = tid; px < 676; px += 256) {
      const int oy = px / 26, ox = px - oy * 26;
      float xw0[9], xw1[9];
#pragma unroll
      for (int r = 0; r < 3; ++r)
#pragma unroll
        for (int cc = 0; cc < 3; ++cc) {
          const int ix = (oy + r) * 28 + ox + cc;
          xw0[r * 3 + cc] = xs0[ix];
          xw1[r * 3 + cc] = xs1[ix];
        }
#pragma unroll
      for (int cw = 0; cw < 8; ++cw) {
        f2 h0 = {0.f, 0.f}, h1 = {0.f, 0.f};
#pragma unroll
        for (int i = 0; i < 9; ++i) {
          const f2 w = w1t2[i * 8 + cw];
          const f2 s0 = {xw0[i], xw0[i]};
          const f2 s1 = {xw1[i], xw1[i]};
          h0 += w * s0;
          h1 += w * s1;
        }
        m = fmaxf(m, fmaxf(fmaxf(fabsf(h0.x), fabsf(h0.y)),
                           fmaxf(fabsf(h1.x), fabsf(h1.y))));
      }
    }
#pragma unroll
    for (int off = 32; off; off >>= 1) m = fmaxf(m, __shfl_down(m, off, 64));
    if ((tid & 63) == 0) wred[tid >> 6] = m;
    __syncthreads();
    if (tid == 0) {
      const float mm = fmaxf(fmaxf(wred[0], wred[1]), fmaxf(wred[2], wred[3]));
      atomicMax(ws + ((int)blockIdx.x & 31), (int)__float_as_uint(mm));
    }
    return;
  }

  const int pb = blockIdx.x - NMAX;  // prep block id 0..55
  if (pb < 10) {
    const int j = pb;
    int s = 0;
    for (int i = tid; i < 3872; i += 256) {
      const float v = wfc[j * 3872 + i];
      s += (v > 0.f) - (v < 0.f);
    }
#pragma unroll
    for (int off = 32; off; off >>= 1) s += __shfl_down(s, off, 64);
    if ((tid & 63) == 0) part[tid >> 6] = s;
    __syncthreads();
    if (tid == 0) {
      const int rs = part[0] + part[1] + part[2] + part[3];
      ((float*)ws)[64 + j] = bfc[j] - (float)rs;  // badj @ dword 64 (byte 256)
    }
    if (pb == 1 && tid < 16) {  // rs2[oc] @ dword 80
      int s2 = 0;
      for (int i = 0; i < 144; ++i) s2 += sgn_pack_byte(w2[tid * 144 + i]);
      ws[80 + tid] = s2;
    }
    if (pb == 2 && tid < 32) {  // rs3[oc] @ dword 96
      int s3 = 0;
      for (int i = 0; i < 144; ++i) s3 += sgn_pack_byte(w3[tid * 144 + i]);
      ws[96 + tid] = s3;
    }
    return;
  }
  int* dst = ws + 128;
  const int widx = (pb - 10) * 256 + tid;
  if (widx < 576) {  // w2m: dword = oc*36 + wp*4 + icg
    const int oc = widx / 36, r = widx % 36, wp = r >> 2, icg = r & 3;
    unsigned wrd = 0;
#pragma unroll
    for (int b = 0; b < 4; ++b) {
      const float v = w2[(oc * 16 + icg * 4 + b) * 9 + wp];
      wrd |= ((unsigned)(uint8_t)(int8_t)sgn_pack_byte(v)) << (8 * b);
    }
    dst[widx] = (int)wrd;
  } else if (widx < 1728) {  // w3m
    const int t = widx - 576;
    const int oc = t / 36, r = t % 36, wp = r >> 2, icg = r & 3;
    unsigned wrd = 0;
#pragma unroll
    for (int b = 0; b < 4; ++b) {
      const float v = w3[(oc * 16 + icg * 4 + b) * 9 + wp];
      wrd |= ((unsigned)(uint8_t)(int8_t)sgn_pack_byte(v)) << (8 * b);
    }
    dst[widx] = (int)wrd;
  } else if (widx < 11408) {  // sw: dword = j*968 + pos*8 + cg
    const int t = widx - 1728;
    const int j = t / 968, r = t % 968, pos = r >> 3, cg = r & 7;
    unsigned wrd = 0;
#pragma unroll
    for (int b = 0; b < 4; ++b) {
      const float v = wfc[j * 3872 + (cg * 4 + b) * 121 + pos];
      wrd |= ((unsigned)(uint8_t)(int8_t)sgn_pack_byte(v)) << (8 * b);
    }
    dst[widx] = (int)wrd;
  }
}

// ---------------------------------------------------------------------------
// Dispatch 2 -- k_forward: ONE image per block. LDS 20456 B -> 8 blocks/CU.
// Layout: a1 @0 (10816 B = 26x26x16; p4 [968 dw] ALIASES a1 head — a1 dead
//   after phase 2) | h2 @10816, PADDED rows: 24 rows x 25 px x 16 B = 9600 B
//   (xs [3136 B] + w1t [576 B] alias h2 head during phases 0-1) |
//   out_acc @20416 (40 B). Reads d_ws only.
// ---------------------------------------------------------------------------
__global__ __launch_bounds__(256) void k_forward(
    const float* __restrict__ x, const float* __restrict__ w1,
    const int* __restrict__ wsd,  // d_ws base (dword-indexed)
    float* __restrict__ out, int B) {
  __shared__ __align__(16) char smem[20456];
  int* out_acc = (int*)(smem + 20416);  // [10]

  const int* wpack = wsd + 128;          // w2m | w3m (w3m at wpack+576)
  const int* sw = wsd + 1856;            // [10][968] dw
  const float* badj = (const float*)(wsd + 64);

  const int tid = threadIdx.x;
  const int img = blockIdx.x;

  // Stage: x -> xs via float4 (196 f4), w1t, out_acc.
  {
    const float4* x4 = (const float4*)(x + (size_t)img * 784);
    if (tid < 196) *(float4*)(smem + 10816 + tid * 16) = x4[tid];
  }
  if (tid < 144) *(float*)(smem + 13952 + ((tid % 9) * 16 + tid / 9) * 4) = w1[tid];
  if (tid < 10) out_acc[tid] = 0;
  __syncthreads();

  // Phase 1: conv1 -> a1 = (s+1) in {0,1,2}. cw chunks of 2, weights hoisted
  // to regs (chunk outer, px inner); per-channel fma chain identical to prep:
  // h += w*s, i ascending, f2 pk form, LDS-staged weight values.
  // Scale = max over the 32 atomic slots (poison slots are negative, lose).
  float mraw = __uint_as_float((unsigned)wsd[0]);
#pragma unroll
  for (int k = 1; k < 32; ++k) mraw = fmaxf(mraw, __uint_as_float((unsigned)wsd[k]));
  const float scale = mraw / 127.0f + 1e-8f;
  const float thr = 0.5f * scale;
  {
    const f2* w1t2 = (const f2*)(smem + 13952);
    const float* xs0 = (const float*)(smem + 10816);
    unsigned wq[3][4] = {};
#pragma unroll
    for (int ch = 0; ch < 4; ++ch) {
      f2 wa[9], wb[9];
#pragma unroll
      for (int i = 0; i < 9; ++i) {
        wa[i] = w1t2[i * 8 + 2 * ch];      // channels 4ch+0,4ch+1
        wb[i] = w1t2[i * 8 + 2 * ch + 1];  // channels 4ch+2,4ch+3
      }
#pragma unroll
      for (int pi = 0; pi < 3; ++pi) {
        const int px = tid + pi * 256;
        if (px < 676) {
          const int oy = px / 26, ox = px - oy * 26;
          float xw[9];
#pragma unroll
          for (int r = 0; r < 3; ++r)
#pragma unroll
            for (int cc = 0; cc < 3; ++cc)
              xw[r * 3 + cc] = xs0[(oy + r) * 28 + ox + cc];
          f2 h0 = {0.f, 0.f}, h1 = {0.f, 0.f};
#pragma unroll
          for (int i = 0; i < 9; ++i) {
            const f2 s = {xw[i], xw[i]};
            h0 += wa[i] * s;
            h1 += wb[i] * s;
          }
          // (s+1): 0 iff h < -thr, 1 iff |h| <= thr, 2 iff h > thr.
          wq[pi][ch] |= ((unsigned)((h0.x >= -thr) + (h0.x > thr))) << 0;
          wq[pi][ch] |= ((unsigned)((h0.y >= -thr) + (h0.y > thr))) << 8;
          wq[pi][ch] |= ((unsigned)((h1.x >= -thr) + (h1.x > thr))) << 16;
          wq[pi][ch] |= ((unsigned)((h1.y >= -thr) + (h1.y > thr))) << 24;
        }
      }
    }
#pragma unroll
    for (int pi = 0; pi < 3; ++pi) {
      const int px = tid + pi * 256;
      if (px < 676)
        *(int4*)(smem + px * 16) =
            make_int4((int)wq[pi][0], (int)wq[pi][1], (int)wq[pi][2], (int)wq[pi][3]);
    }
  }
  __syncthreads();

  // MFMA lane geometry.
  const int lane = tid & 63, wv = tid >> 6;
  const int col = lane & 15, quad = lane >> 4;
  int dAct2[3], dAct3[3];
#pragma unroll
  for (int t = 0; t < 3; ++t) {
    const int wp = t * 4 + quad;  // window pixel (k-block); wp>8 dead (A zeroed)
    dAct2[t] = ((wp / 3) * 26 + wp % 3) * 16;
    dAct3[t] = ((wp / 3) * 25 + wp % 3) * 16;  // h2 stride 25
  }
  const bool kq0 = (quad == 0);  // t=2: only wp=8 is a real k-block

  // Phase 2: conv2. A=sign(w2) frags; acc init = 1 - rs2 (the +1 feeds cl02).
  // h2 written with padded row stride 25 px (400 B).
  {
    const int* wb = wpack + col * 36;  // A-row oc = col
    int4v WA[3];
    WA[0] = *(const int4v*)(wb + quad * 4);
    WA[1] = *(const int4v*)(wb + 16 + quad * 4);
    WA[2] = kq0 ? *(const int4v*)(wb + 32) : (int4v){0, 0, 0, 0};
    const int4v acc0 = (int4v){1, 1, 1, 1} - *(const int4v*)(wsd + 80 + quad * 4);
    const int8_t* a1b = (const int8_t*)smem;
    // incremental (oy,ox) over output pixel p = nt*16+col, nt += 4 (p += 64)
    const int p0 = wv * 16 + col;
    int oy = p0 / 24, ox = p0 - oy * 24;
    const int8_t* abase = a1b + (oy * 26 + ox) * 16;
    int* h2p = (int*)smem + 2704 + (oy * 25 + ox) * 4 + quad;
    for (int it = 0; it < 9; ++it) {
      int4v acc = acc0;
      acc = mfma_i8(WA[0], *(const int4v*)(abase + dAct2[0]), acc);
      acc = mfma_i8(WA[1], *(const int4v*)(abase + dAct2[1]), acc);
      acc = mfma_i8(WA[2], *(const int4v*)(abase + dAct2[2]), acc);
      *h2p = pack4(cl02(acc[0]), cl02(acc[1]), cl02(acc[2]), cl02(acc[3]));
      abase += 1088;  // a1: (oy+=2, ox+=16), stride 26
      h2p += 264;     // h2: (oy+=2, ox+=16), stride 25 (dwords)
      ox += 16;
      if (ox >= 24) { ox -= 24; abase += 32; h2p += 4; }
    }
  }
  __syncthreads();

  // Phase 3: conv3 + in-register pool. Pixels tiled pool-quad-major:
  // tile pt covers cells 4pt..4pt+3; lane col -> cell 4pt+(col>>2), sub col&3.
  // p4 (968 dw) is written into the a1 region (a1 dead after phase 2).
  {
    int4v WA[2][3];
    int4v ac0[2];
#pragma unroll
    for (int ot = 0; ot < 2; ++ot) {
      const int* wb = wpack + 576 + (ot * 16 + col) * 36;
      WA[ot][0] = *(const int4v*)(wb + quad * 4);
      WA[ot][1] = *(const int4v*)(wb + 16 + quad * 4);
      WA[ot][2] = kq0 ? *(const int4v*)(wb + 32) : (int4v){0, 0, 0, 0};
      ac0[ot] = (int4v){1, 1, 1, 1} - *(const int4v*)(wsd + 96 + ot * 16 + quad * 4);
    }
    const int sub = col & 3;
    const int sy = sub >> 1, sx = sub & 1;
    const int cell0 = wv * 4 + (col >> 2);
    const int cy0 = cell0 / 11, cx0 = cell0 - cy0 * 11;
    const int aoff0 = ((cy0 * 2 + sy) * 25 + cx0 * 2 + sx) * 16;
    const int pb0 = cell0 * 8 + quad;
    const int aoffcap = ((20 + sy) * 25 + 20 + sx) * 16;  // cell 120 clamp
    const int pbcap = 120 * 8 + quad;
    const bool wlane = (sub == 0);
    const int8_t* h2b = (const int8_t*)(smem + 10816);
    int* p4 = (int*)smem;
    int aoff = aoff0, pb = pb0, cx = cx0;
    for (int pt = wv; pt < 31; pt += 4) {
      const int8_t* abase = h2b + ((aoff < aoffcap) ? aoff : aoffcap);
      const int pbu = (pb < pbcap) ? pb : pbcap;
      const int4v B0 = *(const int4v*)(abase + dAct3[0]);
      const int4v B1 = *(const int4v*)(abase + dAct3[1]);
      const int4v B2 = *(const int4v*)(abase + dAct3[2]);
#pragma unroll
      for (int ot = 0; ot < 2; ++ot) {
        int4v acc = ac0[ot];
        acc = mfma_i8(WA[ot][0], B0, acc);
        acc = mfma_i8(WA[ot][1], B1, acc);
        acc = mfma_i8(WA[ot][2], B2, acc);
        int s = pack4(cl02(acc[0]), cl02(acc[1]), cl02(acc[2]), cl02(acc[3]));
        // sum (s3+1) packed bytes across the lane nibble (cell's 2x2)
        s += __builtin_amdgcn_update_dpp(0, s, 0xB1, 0xF, 0xF, false);
        s += __builtin_amdgcn_update_dpp(0, s, 0x4E, 0xF, 0xF, false);
        if (wlane) p4[pbu + ot * 4] = s;
      }
      aoff += 960;  // cell += 16: (cy+=1, cx+=5), stride 25
      pb += 128;
      cx += 5;
      if (cx >= 11) { cx -= 11; aoff += 448; }
    }
  }
  __syncthreads();

  // Phase 4: FC. acc = sum n*sw = 4*true + 4*rowsum(sw); badj corrects.
  if (tid < 250) {
    const int j = tid / 25, k = tid - j * 25;
    const int4* p44 = (const int4*)smem;
    int acc = 0;
    for (int pos = k; pos < 121; pos += 25) {
      const int4 pa = p44[pos * 2];
      const int4 pb = p44[pos * 2 + 1];
      const int* swr = sw + j * 968 + pos * 8;
      const int4 wa = *(const int4*)(swr);
      const int4 wbv = *(const int4*)(swr + 4);
      acc = dot4(pa.x, wa.x, acc);
      acc = dot4(pa.y, wa.y, acc);
      acc = dot4(pa.z, wa.z, acc);
      acc = dot4(pa.w, wa.w, acc);
      acc = dot4(pb.x, wbv.x, acc);
      acc = dot4(pb.y, wbv.y, acc);
      acc = dot4(pb.z, wbv.z, acc);
      acc = dot4(pb.w, wbv.w, acc);
    }
    atomicAdd(&out_acc[j], acc);
  }
  __syncthreads();
  if (tid < 10)
    out[(size_t)img * 10 + tid] = 0.25f * (float)out_acc[tid] + badj[tid];
}

extern "C" void kernel_launch(void* const* d_in, const int* in_sizes, int n_in,
                              void* d_out, int out_size, void* d_ws, size_t ws_size,
                              hipStream_t stream) {
  const float* x   = (const float*)d_in[0];
  const float* w1  = (const float*)d_in[1];
  const float* w2  = (const float*)d_in[2];
  const float* w3  = (const float*)d_in[3];
  const float* wfc = (const float*)d_in[4];
  const float* bfc = (const float*)d_in[5];
  float* out = (float*)d_out;
  int* wsd = (int*)d_ws;
  const int B = in_sizes[0] / 784;
  const int NMAX = (B + 1) / 2;

  hipLaunchKernelGGL(k_prep_max, dim3(NMAX + 56), dim3(256), 0, stream,
                     x, w1, w2, w3, wfc, bfc, wsd, B, NMAX);
  hipLaunchKernelGGL(k_forward, dim3(B), dim3(256), 0, stream, x, w1,
                     (const int*)wsd, out, B);
}

// Round 3
// 193.350 us; speedup vs baseline: 1.2937x; 1.0053x over previous
//
#include <hip/hip_runtime.h>
#include <stdint.h>

// ---------------------------------------------------------------------------
// Binarized QAT CNN forward (R17 = R16 + phase-4 conflict kill + VALU trims).
//   - p4 layout: 48 B/cell (12 dw, 8 used) -> 8 bank-groups; FC threads
//     remapped j=u%10, k=u/10 -> 10 lanes broadcast per pos, 7 distinct pos
//     per wave spread over bank-groups -> phase-4 LDS reads conflict-free.
//   - cl02 via v_med3_i32 asm (1 op). Scale reduce via 5x shfl_xor fmax.
//   - R16 bank analysis: phase-2/3 b128 reads are residue-uniform (free);
//     phase-4 was the conflict source (pos*32B -> 4 bank-groups, ~6-way).
//   - k_prep_max unchanged. Remainder (total - k_forward) ~95 us is fixed
//     harness overhead (R16 finding); only k_forward is optimizable.
//
// HARNESS RULE (R12): hipLaunchCooperativeKernel silently fails under graph
// capture here. Two plain dispatches are the minimum; do not retry coop.
// RACE RULE (R8/R9, confirmed R10): the wsmax line (d_ws bytes 0..255) is
// touched ONLY by signed atomicMax (0xAA poison is negative -> loses, so no
// zeroing store exists anywhere); all prep plain-stores live at byte >= 256.
// Slots 0..31 all atomic-only; untouched slots stay poison (negative float,
// loses the fmax reduce in k_forward).
// NUMERICS RULE (R8): conv1 must keep the exact pk-fma form (h += w*s,
// i ascending, LDS-staged weight values) in BOTH kernels — scalar-chain
// rewrites flip boundary decisions.
// NOTE: plain __launch_bounds__(256) — a min-waves arg caps arch VGPRs and
// spills ~50 dw/thread (R4: 426 MB scratch writes). Do not re-add it.
//
// MFMA i8 16x16x64 lane mapping (gfx950): A: lane l holds A[m=l&15][k=16q+j];
// B: B[k=16q+j][n=l&15]; D reg r: row=(l>>4)*4+r, col=l&15. A=weights =>
// A-row oc = col; lane's 4 D values = 4 consecutive channels of one pixel.
// K=144 padded to 192 by zeroing the WEIGHT fragment for k-blocks 9..11.
//
// d_ws layout (dwords): [0..31] wsmax slots (atomic-only line) |
//   [64..73] badj f32[10] | [80..95] rs2 | [96..127] rs3 | [128..703] w2m |
//   [704..1855] w3m | [1856..11535] sw   (total 46144 B)
// ---------------------------------------------------------------------------

typedef int int4v __attribute__((ext_vector_type(4)));
typedef float f2 __attribute__((ext_vector_type(2)));

__device__ __forceinline__ int4v mfma_i8(int4v a, int4v b, int4v c) {
  return __builtin_amdgcn_mfma_i32_16x16x64_i8(a, b, c, 0, 0, 0);
}

__device__ __forceinline__ int dot4(int a, int b, int c) {
#if __has_builtin(__builtin_amdgcn_sdot4)
  return __builtin_amdgcn_sdot4(a, b, c, false);
#else
  int r = c;
  r += (int)(int8_t)(a)       * (int)(int8_t)(b);
  r += (int)(int8_t)(a >> 8)  * (int)(int8_t)(b >> 8);
  r += (int)(int8_t)(a >> 16) * (int)(int8_t)(b >> 16);
  r += (int)(int8_t)(a >> 24) * (int)(int8_t)(b >> 24);
  return r;
#endif
}

// Pack low bytes of r0..r3 into one dword: [r0b0|r1b0|r2b0|r3b0].
__device__ __forceinline__ int pack4(int r0, int r1, int r2, int r3) {
  const int t0 = __builtin_amdgcn_perm(r1, r0, 0x00000400);
  const int t1 = __builtin_amdgcn_perm(r3, r2, 0x00000400);
  return __builtin_amdgcn_perm(t1, t0, 0x05040100);
}

// med3(v,0,2) in one VALU op; acc init carries the +1 so this is the epilogue.
__device__ __forceinline__ int cl02(int v) {
  int r;
  asm("v_med3_i32 %0, %1, 0, 2" : "=v"(r) : "v"(v));
  return r;
}

__device__ __forceinline__ int sgn_pack_byte(float v) {
  return (v > 0.f) - (v < 0.f);
}

// Dispatch 1 -- merged conv1-max + prep (unchanged from R15).
__global__ __launch_bounds__(256) void k_prep_max(
    const float* __restrict__ x, const float* __restrict__ w1,
    const float* __restrict__ w2, const float* __restrict__ w3,
    const float* __restrict__ wfc, const float* __restrict__ bfc,
    int* __restrict__ ws, int B, int NMAX) {
  __shared__ __align__(16) float xs[1568];
  __shared__ __align__(8) float w1t[144];
  __shared__ float wred[4];
  __shared__ int part[4];

  const int tid = threadIdx.x;
  if ((int)blockIdx.x < NMAX) {
    const int img0 = blockIdx.x * 2;
    const bool has1 = (img0 + 1) < B;
    {
      const float4* x4a = (const float4*)(x + (size_t)img0 * 784);
      const float4* x4b = (const float4*)(x + (size_t)(img0 + (int)has1) * 784);
      for (int u = tid; u < 392; u += 256) {
        const int im = (u >= 196), i = im ? u - 196 : u;
        const float4 v = im ? x4b[i] : x4a[i];
        *(float4*)&xs[im * 784 + i * 4] = v;
      }
    }
    if (tid < 144) w1t[(tid % 9) * 16 + tid / 9] = w1[tid];
    __syncthreads();
    const f2* w1t2 = (const f2*)w1t;
    const float* xs0 = xs;
    const float* xs1 = xs + 784;
    float m = 0.f;
    for (int px = tid; px < 676; px += 256) {
      const int oy = px / 26, ox = px - oy * 26;
      float xw0[9], xw1[9];
#pragma unroll
      for (int r = 0; r < 3; ++r)
#pragma unroll
        for (int cc = 0; cc < 3; ++cc) {
          const int ix = (oy + r) * 28 + ox + cc;
          xw0[r * 3 + cc] = xs0[ix];
          xw1[r * 3 + cc] = xs1[ix];
        }
#pragma unroll
      for (int cw = 0; cw < 8; ++cw) {
        f2 h0 = {0.f, 0.f}, h1 = {0.f, 0.f};
#pragma unroll
        for (int i = 0; i < 9; ++i) {
          const f2 w = w1t2[i * 8 + cw];
          const f2 s0 = {xw0[i], xw0[i]};
          const f2 s1 = {xw1[i], xw1[i]};
          h0 += w * s0;
          h1 += w * s1;
        }
        m = fmaxf(m, fmaxf(fmaxf(fabsf(h0.x), fabsf(h0.y)),
                           fmaxf(fabsf(h1.x), fabsf(h1.y))));
      }
    }
#pragma unroll
    for (int off = 32; off; off >>= 1) m = fmaxf(m, __shfl_down(m, off, 64));
    if ((tid & 63) == 0) wred[tid >> 6] = m;
    __syncthreads();
    if (tid == 0) {
      const float mm = fmaxf(fmaxf(wred[0], wred[1]), fmaxf(wred[2], wred[3]));
      atomicMax(ws + ((int)blockIdx.x & 31), (int)__float_as_uint(mm));
    }
    return;
  }

  const int pb = blockIdx.x - NMAX;  // prep block id 0..55
  if (pb < 10) {
    const int j = pb;
    int s = 0;
    for (int i = tid; i < 3872; i += 256) {
      const float v = wfc[j * 3872 + i];
      s += (v > 0.f) - (v < 0.f);
    }
#pragma unroll
    for (int off = 32; off; off >>= 1) s += __shfl_down(s, off, 64);
    if ((tid & 63) == 0) part[tid >> 6] = s;
    __syncthreads();
    if (tid == 0) {
      const int rs = part[0] + part[1] + part[2] + part[3];
      ((float*)ws)[64 + j] = bfc[j] - (float)rs;  // badj @ dword 64 (byte 256)
    }
    if (pb == 1 && tid < 16) {  // rs2[oc] @ dword 80
      int s2 = 0;
      for (int i = 0; i < 144; ++i) s2 += sgn_pack_byte(w2[tid * 144 + i]);
      ws[80 + tid] = s2;
    }
    if (pb == 2 && tid < 32) {  // rs3[oc] @ dword 96
      int s3 = 0;
      for (int i = 0; i < 144; ++i) s3 += sgn_pack_byte(w3[tid * 144 + i]);
      ws[96 + tid] = s3;
    }
    return;
  }
  int* dst = ws + 128;
  const int widx = (pb - 10) * 256 + tid;
  if (widx < 576) {  // w2m: dword = oc*36 + wp*4 + icg
    const int oc = widx / 36, r = widx % 36, wp = r >> 2, icg = r & 3;
    unsigned wrd = 0;
#pragma unroll
    for (int b = 0; b < 4; ++b) {
      const float v = w2[(oc * 16 + icg * 4 + b) * 9 + wp];
      wrd |= ((unsigned)(uint8_t)(int8_t)sgn_pack_byte(v)) << (8 * b);
    }
    dst[widx] = (int)wrd;
  } else if (widx < 1728) {  // w3m
    const int t = widx - 576;
    const int oc = t / 36, r = t % 36, wp = r >> 2, icg = r & 3;
    unsigned wrd = 0;
#pragma unroll
    for (int b = 0; b < 4; ++b) {
      const float v = w3[(oc * 16 + icg * 4 + b) * 9 + wp];
      wrd |= ((unsigned)(uint8_t)(int8_t)sgn_pack_byte(v)) << (8 * b);
    }
    dst[widx] = (int)wrd;
  } else if (widx < 11408) {  // sw: dword = j*968 + pos*8 + cg
    const int t = widx - 1728;
    const int j = t / 968, r = t % 968, pos = r >> 3, cg = r & 7;
    unsigned wrd = 0;
#pragma unroll
    for (int b = 0; b < 4; ++b) {
      const float v = wfc[j * 3872 + (cg * 4 + b) * 121 + pos];
      wrd |= ((unsigned)(uint8_t)(int8_t)sgn_pack_byte(v)) << (8 * b);
    }
    dst[widx] = (int)wrd;
  }
}

// ---------------------------------------------------------------------------
// Dispatch 2 -- k_forward: ONE image per block. LDS 20456 B -> 8 blocks/CU.
// Layout: a1 @0 (10816 B = 26x26x16; p4 [121 cells x 12 dw = 48 B stride,
//   5808 B] ALIASES a1 head — a1 dead after phase 2) | h2 @10816, PADDED
//   rows: 24 rows x 25 px x 16 B = 9600 B (xs [3136 B] + w1t [576 B] alias
//   h2 head during phases 0-1) | out_acc @20416 (40 B). Reads d_ws only.
// ---------------------------------------------------------------------------
__global__ __launch_bounds__(256) void k_forward(
    const float* __restrict__ x, const float* __restrict__ w1,
    const int* __restrict__ wsd,  // d_ws base (dword-indexed)
    float* __restrict__ out, int B) {
  __shared__ __align__(16) char smem[20456];
  int* out_acc = (int*)(smem + 20416);  // [10]

  const int* wpack = wsd + 128;          // w2m | w3m (w3m at wpack+576)
  const int* sw = wsd + 1856;            // [10][968] dw
  const float* badj = (const float*)(wsd + 64);

  const int tid = threadIdx.x;
  const int img = blockIdx.x;

  // Early: this lane's wsmax slot (atomic-only line; poison is negative).
  const float slotv = __uint_as_float((unsigned)wsd[tid & 31]);

  // Stage: x -> xs via float4 (196 f4), w1t, out_acc.
  {
    const float4* x4 = (const float4*)(x + (size_t)img * 784);
    if (tid < 196) *(float4*)(smem + 10816 + tid * 16) = x4[tid];
  }
  if (tid < 144) *(float*)(smem + 13952 + ((tid % 9) * 16 + tid / 9) * 4) = w1[tid];
  if (tid < 10) out_acc[tid] = 0;
  __syncthreads();

  // Phase 1: conv1 -> a1 = (s+1) in {0,1,2}. cw chunks of 2, weights hoisted
  // to regs (chunk outer, px inner); per-channel fma chain identical to prep:
  // h += w*s, i ascending, f2 pk form, LDS-staged weight values.
  // Scale = wave-butterfly max over the 32 slots (fmax reorder is exact).
  float mraw = slotv;
#pragma unroll
  for (int off = 16; off; off >>= 1) mraw = fmaxf(mraw, __shfl_xor(mraw, off, 64));
  const float scale = mraw / 127.0f + 1e-8f;
  const float thr = 0.5f * scale;
  {
    const f2* w1t2 = (const f2*)(smem + 13952);
    const float* xs0 = (const float*)(smem + 10816);
    unsigned wq[3][4] = {};
#pragma unroll
    for (int ch = 0; ch < 4; ++ch) {
      f2 wa[9], wb[9];
#pragma unroll
      for (int i = 0; i < 9; ++i) {
        wa[i] = w1t2[i * 8 + 2 * ch];      // channels 4ch+0,4ch+1
        wb[i] = w1t2[i * 8 + 2 * ch + 1];  // channels 4ch+2,4ch+3
      }
#pragma unroll
      for (int pi = 0; pi < 3; ++pi) {
        const int px = tid + pi * 256;
        if (px < 676) {
          const int oy = px / 26, ox = px - oy * 26;
          float xw[9];
#pragma unroll
          for (int r = 0; r < 3; ++r)
#pragma unroll
            for (int cc = 0; cc < 3; ++cc)
              xw[r * 3 + cc] = xs0[(oy + r) * 28 + ox + cc];
          f2 h0 = {0.f, 0.f}, h1 = {0.f, 0.f};
#pragma unroll
          for (int i = 0; i < 9; ++i) {
            const f2 s = {xw[i], xw[i]};
            h0 += wa[i] * s;
            h1 += wb[i] * s;
          }
          // (s+1): 0 iff h < -thr, 1 iff |h| <= thr, 2 iff h > thr.
          wq[pi][ch] |= ((unsigned)((h0.x >= -thr) + (h0.x > thr))) << 0;
          wq[pi][ch] |= ((unsigned)((h0.y >= -thr) + (h0.y > thr))) << 8;
          wq[pi][ch] |= ((unsigned)((h1.x >= -thr) + (h1.x > thr))) << 16;
          wq[pi][ch] |= ((unsigned)((h1.y >= -thr) + (h1.y > thr))) << 24;
        }
      }
    }
#pragma unroll
    for (int pi = 0; pi < 3; ++pi) {
      const int px = tid + pi * 256;
      if (px < 676)
        *(int4*)(smem + px * 16) =
            make_int4((int)wq[pi][0], (int)wq[pi][1], (int)wq[pi][2], (int)wq[pi][3]);
    }
  }
  __syncthreads();

  // MFMA lane geometry.
  const int lane = tid & 63, wv = tid >> 6;
  const int col = lane & 15, quad = lane >> 4;
  int dAct2[3], dAct3[3];
#pragma unroll
  for (int t = 0; t < 3; ++t) {
    const int wp = t * 4 + quad;  // window pixel (k-block); wp>8 dead (A zeroed)
    dAct2[t] = ((wp / 3) * 26 + wp % 3) * 16;
    dAct3[t] = ((wp / 3) * 25 + wp % 3) * 16;  // h2 stride 25
  }
  const bool kq0 = (quad == 0);  // t=2: only wp=8 is a real k-block

  // Phase 2: conv2. A=sign(w2) frags; acc init = 1 - rs2 (the +1 feeds cl02).
  // h2 written with padded row stride 25 px (400 B).
  {
    const int* wb = wpack + col * 36;  // A-row oc = col
    int4v WA[3];
    WA[0] = *(const int4v*)(wb + quad * 4);
    WA[1] = *(const int4v*)(wb + 16 + quad * 4);
    WA[2] = kq0 ? *(const int4v*)(wb + 32) : (int4v){0, 0, 0, 0};
    const int4v acc0 = (int4v){1, 1, 1, 1} - *(const int4v*)(wsd + 80 + quad * 4);
    const int8_t* a1b = (const int8_t*)smem;
    // incremental (oy,ox) over output pixel p = nt*16+col, nt += 4 (p += 64)
    const int p0 = wv * 16 + col;
    int oy = p0 / 24, ox = p0 - oy * 24;
    const int8_t* abase = a1b + (oy * 26 + ox) * 16;
    int* h2p = (int*)smem + 2704 + (oy * 25 + ox) * 4 + quad;
    for (int it = 0; it < 9; ++it) {
      int4v acc = acc0;
      acc = mfma_i8(WA[0], *(const int4v*)(abase + dAct2[0]), acc);
      acc = mfma_i8(WA[1], *(const int4v*)(abase + dAct2[1]), acc);
      acc = mfma_i8(WA[2], *(const int4v*)(abase + dAct2[2]), acc);
      *h2p = pack4(cl02(acc[0]), cl02(acc[1]), cl02(acc[2]), cl02(acc[3]));
      abase += 1088;  // a1: (oy+=2, ox+=16), stride 26
      h2p += 264;     // h2: (oy+=2, ox+=16), stride 25 (dwords)
      ox += 16;
      if (ox >= 24) { ox -= 24; abase += 32; h2p += 4; }
    }
  }
  __syncthreads();

  // Phase 3: conv3 + in-register pool. Pixels tiled pool-quad-major:
  // tile pt covers cells 4pt..4pt+3; lane col -> cell 4pt+(col>>2), sub col&3.
  // p4 (48 B/cell stride) is written into the a1 region (a1 dead).
  {
    int4v WA[2][3];
    int4v ac0[2];
#pragma unroll
    for (int ot = 0; ot < 2; ++ot) {
      const int* wb = wpack + 576 + (ot * 16 + col) * 36;
      WA[ot][0] = *(const int4v*)(wb + quad * 4);
      WA[ot][1] = *(const int4v*)(wb + 16 + quad * 4);
      WA[ot][2] = kq0 ? *(const int4v*)(wb + 32) : (int4v){0, 0, 0, 0};
      ac0[ot] = (int4v){1, 1, 1, 1} - *(const int4v*)(wsd + 96 + ot * 16 + quad * 4);
    }
    const int sub = col & 3;
    const int sy = sub >> 1, sx = sub & 1;
    const int cell0 = wv * 4 + (col >> 2);
    const int cy0 = cell0 / 11, cx0 = cell0 - cy0 * 11;
    const int aoff0 = ((cy0 * 2 + sy) * 25 + cx0 * 2 + sx) * 16;
    const int pb0 = cell0 * 12 + quad;
    const int aoffcap = ((20 + sy) * 25 + 20 + sx) * 16;  // cell 120 clamp
    const int pbcap = 120 * 12 + quad;
    const bool wlane = (sub == 0);
    const int8_t* h2b = (const int8_t*)(smem + 10816);
    int* p4 = (int*)smem;
    int aoff = aoff0, pb = pb0, cx = cx0;
    for (int pt = wv; pt < 31; pt += 4) {
      const int8_t* abase = h2b + ((aoff < aoffcap) ? aoff : aoffcap);
      const int pbu = (pb < pbcap) ? pb : pbcap;
      const int4v B0 = *(const int4v*)(abase + dAct3[0]);
      const int4v B1 = *(const int4v*)(abase + dAct3[1]);
      const int4v B2 = *(const int4v*)(abase + dAct3[2]);
#pragma unroll
      for (int ot = 0; ot < 2; ++ot) {
        int4v acc = ac0[ot];
        acc = mfma_i8(WA[ot][0], B0, acc);
        acc = mfma_i8(WA[ot][1], B1, acc);
        acc = mfma_i8(WA[ot][2], B2, acc);
        int s = pack4(cl02(acc[0]), cl02(acc[1]), cl02(acc[2]), cl02(acc[3]));
        // sum (s3+1) packed bytes across the lane nibble (cell's 2x2)
        s += __builtin_amdgcn_update_dpp(0, s, 0xB1, 0xF, 0xF, false);
        s += __builtin_amdgcn_update_dpp(0, s, 0x4E, 0xF, 0xF, false);
        if (wlane) p4[pbu + ot * 4] = s;
      }
      aoff += 960;  // cell += 16: (cy+=1, cx+=5), stride 25
      pb += 192;    // cell += 16, stride 12 dw
      cx += 5;
      if (cx >= 11) { cx -= 11; aoff += 448; }
    }
  }
  __syncthreads();

  // Phase 4: FC. acc = sum n*sw = 4*true + 4*rowsum(sw); badj corrects.
  // Mapping j=u%10, k=u/10: 10 lanes share each pos (LDS broadcast reads,
  // conflict-free with the 48 B cell stride); atomics 7-way per out_acc[j].
  if (tid < 250) {
    const int j = tid % 10, k = tid / 10;
    const int* p4d = (const int*)smem;
    int acc = 0;
    for (int pos = k; pos < 121; pos += 25) {
      const int4 pa = *(const int4*)(p4d + pos * 12);
      const int4 pb = *(const int4*)(p4d + pos * 12 + 4);
      const int* swr = sw + j * 968 + pos * 8;
      const int4 wa = *(const int4*)(swr);
      const int4 wbv = *(const int4*)(swr + 4);
      acc = dot4(pa.x, wa.x, acc);
      acc = dot4(pa.y, wa.y, acc);
      acc = dot4(pa.z, wa.z, acc);
      acc = dot4(pa.w, wa.w, acc);
      acc = dot4(pb.x, wbv.x, acc);
      acc = dot4(pb.y, wbv.y, acc);
      acc = dot4(pb.z, wbv.z, acc);
      acc = dot4(pb.w, wbv.w, acc);
    }
    atomicAdd(&out_acc[j], acc);
  }
  __syncthreads();
  if (tid < 10)
    out[(size_t)img * 10 + tid] = 0.25f * (float)out_acc[tid] + badj[tid];
}

extern "C" void kernel_launch(void* const* d_in, const int* in_sizes, int n_in,
                              void* d_out, int out_size, void* d_ws, size_t ws_size,
                              hipStream_t stream) {
  const float* x   = (const float*)d_in[0];
  const float* w1  = (const float*)d_in[1];
  const float* w2  = (const float*)d_in[2];
  const float* w3  = (const float*)d_in[3];
  const float* wfc = (const float*)d_in[4];
  const float* bfc = (const float*)d_in[5];
  float* out = (float*)d_out;
  int* wsd = (int*)d_ws;
  const int B = in_sizes[0] / 784;
  const int NMAX = (B + 1) / 2;

  hipLaunchKernelGGL(k_prep_max, dim3(NMAX + 56), dim3(256), 0, stream,
                     x, w1, w2, w3, wfc, bfc, wsd, B, NMAX);
  hipLaunchKernelGGL(k_forward, dim3(B), dim3(256), 0, stream, x, w1,
                     (const int*)wsd, out, B);
}

// Round 6
// 193.205 us; speedup vs baseline: 1.2947x; 1.0007x over previous
//
#include <hip/hip_runtime.h>
#include <stdint.h>

// ---------------------------------------------------------------------------
// Binarized QAT CNN forward (R19 = R17 + safe trims; swizzle REVERTED).
//   - R18 LESSON (absmax 69): XOR-bit6-by-row-parity LDS swizzle is NON-
//     BIJECTIVE when row stride is not a 128 B multiple (a1 416 B, h2 400 B):
//     16p ^ 64 = 16(p^4), and p^4 can cross into an adjacent row with the
//     other parity -> two pixels collide on one address (e.g. a1 (1,22) vs
//     (2,0)). Any future swizzle must derive its mask from address bits
//     ABOVE the XORed bit (involutive), or pad rows to 128-mult.
//   - Conflict model correction: R17 phase-2/3 b128 reads are residue-
//     uniform (16 consecutive cells/quad cover all 8 bank-groups evenly);
//     the 12M counter is low-order b128 phasing, largely hidden at 8
//     blocks/CU. Kernel is VALU-issue-bound (VALUBusy 80%) — optimize
//     instruction count, not LDS layout.
//   - R19 trims (all bit-exact): phase-1 hoisted px bases + act flags;
//     quant bytes packed via pack4 perms; dead-B broadcast for t=2 MFMA
//     operand (wp=8 address for ALL quads, values zeroed via A fragment).
//   - k_prep_max unchanged. NOTE: remainder (total - k_forward) ~95 us =
//     k_prep_max (conv1-max over all images, ~phase-1-equivalent work) +
//     launch overhead; prep cannot be skipped (scale needs global max
//     before any quantization) and streams/coop are unavailable (R12).
//
// HARNESS RULE (R12): hipLaunchCooperativeKernel silently fails under graph
// capture here. Two plain dispatches are the minimum; do not retry coop.
// RACE RULE (R8/R9, confirmed R10): the wsmax line (d_ws bytes 0..255) is
// touched ONLY by signed atomicMax (0xAA poison is negative -> loses, so no
// zeroing store exists anywhere); all prep plain-stores live at byte >= 256.
// Slots 0..31 all atomic-only; untouched slots stay poison (negative float,
// loses the fmax reduce in k_forward).
// NUMERICS RULE (R8): conv1 must keep the exact pk-fma form (h += w*s,
// i ascending, LDS-staged weight values) in BOTH kernels — scalar-chain
// rewrites flip boundary decisions.
// NOTE: plain __launch_bounds__(256) — a min-waves arg caps arch VGPRs and
// spills ~50 dw/thread (R4: 426 MB scratch writes). Do not re-add it.
//
// MFMA i8 16x16x64 lane mapping (gfx950): A: lane l holds A[m=l&15][k=16q+j];
// B: B[k=16q+j][n=l&15]; D reg r: row=(l>>4)*4+r, col=l&15. A=weights =>
// A-row oc = col; lane's 4 D values = 4 consecutive channels of one pixel.
// K=144 padded to 192 by zeroing the WEIGHT fragment for k-blocks 9..11.
//
// d_ws layout (dwords): [0..31] wsmax slots (atomic-only line) |
//   [64..73] badj f32[10] | [80..95] rs2 | [96..127] rs3 | [128..703] w2m |
//   [704..1855] w3m | [1856..11535] sw   (total 46144 B)
//
// k_forward LDS map (20456 B, 8 blocks/CU):
//   a1 [0, 10816): 26x26 px x 16 B; p4 [121 cells x 48 B = 5808 B] aliases
//     head (a1 dead in phases 3+).
//   h2 [10816, 20416): 24 rows x 25 px x 16 B (col 24 = pad); xs [3136 B] +
//     w1t [576 B] alias head during phases 0-1.
//   out_acc @20416 (40 B).
// ---------------------------------------------------------------------------

typedef int int4v __attribute__((ext_vector_type(4)));
typedef float f2 __attribute__((ext_vector_type(2)));

__device__ __forceinline__ int4v mfma_i8(int4v a, int4v b, int4v c) {
  return __builtin_amdgcn_mfma_i32_16x16x64_i8(a, b, c, 0, 0, 0);
}

__device__ __forceinline__ int dot4(int a, int b, int c) {
#if __has_builtin(__builtin_amdgcn_sdot4)
  return __builtin_amdgcn_sdot4(a, b, c, false);
#else
  int r = c;
  r += (int)(int8_t)(a)       * (int)(int8_t)(b);
  r += (int)(int8_t)(a >> 8)  * (int)(int8_t)(b >> 8);
  r += (int)(int8_t)(a >> 16) * (int)(int8_t)(b >> 16);
  r += (int)(int8_t)(a >> 24) * (int)(int8_t)(b >> 24);
  return r;
#endif
}

// Pack low bytes of r0..r3 into one dword: [r0b0|r1b0|r2b0|r3b0].
__device__ __forceinline__ int pack4(int r0, int r1, int r2, int r3) {
  const int t0 = __builtin_amdgcn_perm(r1, r0, 0x00000400);
  const int t1 = __builtin_amdgcn_perm(r3, r2, 0x00000400);
  return __builtin_amdgcn_perm(t1, t0, 0x05040100);
}

// med3(v,0,2) in one VALU op; acc init carries the +1 so this is the epilogue.
__device__ __forceinline__ int cl02(int v) {
  int r;
  asm("v_med3_i32 %0, %1, 0, 2" : "=v"(r) : "v"(v));
  return r;
}

__device__ __forceinline__ int sgn_pack_byte(float v) {
  return (v > 0.f) - (v < 0.f);
}

// Dispatch 1 -- merged conv1-max + prep (unchanged from R15).
__global__ __launch_bounds__(256) void k_prep_max(
    const float* __restrict__ x, const float* __restrict__ w1,
    const float* __restrict__ w2, const float* __restrict__ w3,
    const float* __restrict__ wfc, const float* __restrict__ bfc,
    int* __restrict__ ws, int B, int NMAX) {
  __shared__ __align__(16) float xs[1568];
  __shared__ __align__(8) float w1t[144];
  __shared__ float wred[4];
  __shared__ int part[4];

  const int tid = threadIdx.x;
  if ((int)blockIdx.x < NMAX) {
    const int img0 = blockIdx.x * 2;
    const bool has1 = (img0 + 1) < B;
    {
      const float4* x4a = (const float4*)(x + (size_t)img0 * 784);
      const float4* x4b = (const float4*)(x + (size_t)(img0 + (int)has1) * 784);
      for (int u = tid; u < 392; u += 256) {
        const int im = (u >= 196), i = im ? u - 196 : u;
        const float4 v = im ? x4b[i] : x4a[i];
        *(float4*)&xs[im * 784 + i * 4] = v;
      }
    }
    if (tid < 144) w1t[(tid % 9) * 16 + tid / 9] = w1[tid];
    __syncthreads();
    const f2* w1t2 = (const f2*)w1t;
    const float* xs0 = xs;
    const float* xs1 = xs + 784;
    float m = 0.f;
    for (int px = tid; px < 676; px += 256) {
      const int oy = px / 26, ox = px - oy * 26;
      float xw0[9], xw1[9];
#pragma unroll
      for (int r = 0; r < 3; ++r)
#pragma unroll
        for (int cc = 0; cc < 3; ++cc) {
          const int ix = (oy + r) * 28 + ox + cc;
          xw0[r * 3 + cc] = xs0[ix];
          xw1[r * 3 + cc] = xs1[ix];
        }
#pragma unroll
      for (int cw = 0; cw < 8; ++cw) {
        f2 h0 = {0.f, 0.f}, h1 = {0.f, 0.f};
#pragma unroll
        for (int i = 0; i < 9; ++i) {
          const f2 w = w1t2[i * 8 + cw];
          const f2 s0 = {xw0[i], xw0[i]};
          const f2 s1 = {xw1[i], xw1[i]};
          h0 += w * s0;
          h1 += w * s1;
        }
        m = fmaxf(m, fmaxf(fmaxf(fabsf(h0.x), fabsf(h0.y)),
                           fmaxf(fabsf(h1.x), fabsf(h1.y))));
      }
    }
#pragma unroll
    for (int off = 32; off; off >>= 1) m = fmaxf(m, __shfl_down(m, off, 64));
    if ((tid & 63) == 0) wred[tid >> 6] = m;
    __syncthreads();
    if (tid == 0) {
      const float mm = fmaxf(fmaxf(wred[0], wred[1]), fmaxf(wred[2], wred[3]));
      atomicMax(ws + ((int)blockIdx.x & 31), (int)__float_as_uint(mm));
    }
    return;
  }

  const int pb = blockIdx.x - NMAX;  // prep block id 0..55
  if (pb < 10) {
    const int j = pb;
    int s = 0;
    for (int i = tid; i < 3872; i += 256) {
      const float v = wfc[j * 3872 + i];
      s += (v > 0.f) - (v < 0.f);
    }
#pragma unroll
    for (int off = 32; off; off >>= 1) s += __shfl_down(s, off, 64);
    if ((tid & 63) == 0) part[tid >> 6] = s;
    __syncthreads();
    if (tid == 0) {
      const int rs = part[0] + part[1] + part[2] + part[3];
      ((float*)ws)[64 + j] = bfc[j] - (float)rs;  // badj @ dword 64 (byte 256)
    }
    if (pb == 1 && tid < 16) {  // rs2[oc] @ dword 80
      int s2 = 0;
      for (int i = 0; i < 144; ++i) s2 += sgn_pack_byte(w2[tid * 144 + i]);
      ws[80 + tid] = s2;
    }
    if (pb == 2 && tid < 32) {  // rs3[oc] @ dword 96
      int s3 = 0;
      for (int i = 0; i < 144; ++i) s3 += sgn_pack_byte(w3[tid * 144 + i]);
      ws[96 + tid] = s3;
    }
    return;
  }
  int* dst = ws + 128;
  const int widx = (pb - 10) * 256 + tid;
  if (widx < 576) {  // w2m: dword = oc*36 + wp*4 + icg
    const int oc = widx / 36, r = widx % 36, wp = r >> 2, icg = r & 3;
    unsigned wrd = 0;
#pragma unroll
    for (int b = 0; b < 4; ++b) {
      const float v = w2[(oc * 16 + icg * 4 + b) * 9 + wp];
      wrd |= ((unsigned)(uint8_t)(int8_t)sgn_pack_byte(v)) << (8 * b);
    }
    dst[widx] = (int)wrd;
  } else if (widx < 1728) {  // w3m
    const int t = widx - 576;
    const int oc = t / 36, r = t % 36, wp = r >> 2, icg = r & 3;
    unsigned wrd = 0;
#pragma unroll
    for (int b = 0; b < 4; ++b) {
      const float v = w3[(oc * 16 + icg * 4 + b) * 9 + wp];
      wrd |= ((unsigned)(uint8_t)(int8_t)sgn_pack_byte(v)) << (8 * b);
    }
    dst[widx] = (int)wrd;
  } else if (widx < 11408) {  // sw: dword = j*968 + pos*8 + cg
    const int t = widx - 1728;
    const int j = t / 968, r = t % 968, pos = r >> 3, cg = r & 7;
    unsigned wrd = 0;
#pragma unroll
    for (int b = 0; b < 4; ++b) {
      const float v = wfc[j * 3872 + (cg * 4 + b) * 121 + pos];
      wrd |= ((unsigned)(uint8_t)(int8_t)sgn_pack_byte(v)) << (8 * b);
    }
    dst[widx] = (int)wrd;
  }
}

// ---------------------------------------------------------------------------
// Dispatch 2 -- k_forward: ONE image per block. LDS 20456 B -> 8 blocks/CU.
// ---------------------------------------------------------------------------
__global__ __launch_bounds__(256) void k_forward(
    const float* __restrict__ x, const float* __restrict__ w1,
    const int* __restrict__ wsd,  // d_ws base (dword-indexed)
    float* __restrict__ out, int B) {
  __shared__ __align__(16) char smem[20456];
  int* out_acc = (int*)(smem + 20416);  // [10]

  const int* wpack = wsd + 128;          // w2m | w3m (w3m at wpack+576)
  const int* sw = wsd + 1856;            // [10][968] dw
  const float* badj = (const float*)(wsd + 64);

  const int tid = threadIdx.x;
  const int img = blockIdx.x;

  // Early: this lane's wsmax slot (atomic-only line; poison is negative).
  const float slotv = __uint_as_float((unsigned)wsd[tid & 31]);

  // Stage: x -> xs @10816 via float4 (196 f4), w1t @13952, out_acc.
  {
    const float4* x4 = (const float4*)(x + (size_t)img * 784);
    if (tid < 196) *(float4*)(smem + 10816 + tid * 16) = x4[tid];
  }
  if (tid < 144) *(float*)(smem + 13952 + ((tid % 9) * 16 + tid / 9) * 4) = w1[tid];
  if (tid < 10) out_acc[tid] = 0;
  __syncthreads();

  // Phase 1: conv1 -> a1 = (s+1) in {0,1,2}. cw chunks of 2, weights hoisted
  // to regs (chunk outer, px inner); per-channel fma chain identical to prep:
  // h += w*s, i ascending, f2 pk form, LDS-staged weight values.
  // Scale = wave-butterfly max over the 32 slots (fmax reorder is exact).
  float mraw = slotv;
#pragma unroll
  for (int off = 16; off; off >>= 1) mraw = fmaxf(mraw, __shfl_xor(mraw, off, 64));
  const float scale = mraw / 127.0f + 1e-8f;
  const float thr = 0.5f * scale;
  {
    const f2* w1t2 = (const f2*)(smem + 13952);
    int xsb[3], a1o[3];
    bool act[3];
#pragma unroll
    for (int pi = 0; pi < 3; ++pi) {
      const int px = tid + pi * 256;
      act[pi] = px < 676;
      const int oy = px / 26, ox = px - oy * 26;
      xsb[pi] = 10816 + (oy * 28 + ox) * 4;
      a1o[pi] = px * 16;
    }
    unsigned wq[3][4];
#pragma unroll
    for (int ch = 0; ch < 4; ++ch) {
      f2 wa[9], wb9[9];
#pragma unroll
      for (int i = 0; i < 9; ++i) {
        wa[i] = w1t2[i * 8 + 2 * ch];      // channels 4ch+0,4ch+1
        wb9[i] = w1t2[i * 8 + 2 * ch + 1]; // channels 4ch+2,4ch+3
      }
#pragma unroll
      for (int pi = 0; pi < 3; ++pi) {
        if (act[pi]) {
          const char* bp = smem + xsb[pi];
          float xw[9];
#pragma unroll
          for (int r = 0; r < 3; ++r)
#pragma unroll
            for (int cc = 0; cc < 3; ++cc)
              xw[r * 3 + cc] = *(const float*)(bp + r * 112 + cc * 4);
          f2 h0 = {0.f, 0.f}, h1 = {0.f, 0.f};
#pragma unroll
          for (int i = 0; i < 9; ++i) {
            const f2 s = {xw[i], xw[i]};
            h0 += wa[i] * s;
            h1 += wb9[i] * s;
          }
          // (s+1): 0 iff h < -thr, 1 iff |h| <= thr, 2 iff h > thr.
          const int b0 = (h0.x >= -thr) + (h0.x > thr);
          const int b1 = (h0.y >= -thr) + (h0.y > thr);
          const int b2 = (h1.x >= -thr) + (h1.x > thr);
          const int b3 = (h1.y >= -thr) + (h1.y > thr);
          wq[pi][ch] = (unsigned)pack4(b0, b1, b2, b3);
        }
      }
    }
#pragma unroll
    for (int pi = 0; pi < 3; ++pi)
      if (act[pi])
        *(int4*)(smem + a1o[pi]) =
            make_int4((int)wq[pi][0], (int)wq[pi][1], (int)wq[pi][2], (int)wq[pi][3]);
  }
  __syncthreads();

  // MFMA lane geometry. t=2 uses wp=8 for ALL quads (dead-B broadcast:
  // quads 1-3 have zero-A so values are ignored; same-address read is free
  // and keeps the operand inside the live region).
  const int lane = tid & 63, wv = tid >> 6;
  const int col = lane & 15, quad = lane >> 4;
  int off2[3], off3[3];
#pragma unroll
  for (int t = 0; t < 3; ++t) {
    const int wp = (t < 2) ? (t * 4 + quad) : 8;
    const int wr = wp / 3, wc = wp - wr * 3;
    off2[t] = (wr * 26 + wc) * 16;  // a1 stride 26 px
    off3[t] = (wr * 25 + wc) * 16;  // h2 stride 25 px
  }
  const bool kq0 = (quad == 0);

  // Phase 2: conv2. A=sign(w2) frags; acc init = 1 - rs2 (the +1 feeds cl02).
  // h2 written with padded row stride 25 px (400 B).
  {
    const int* wb = wpack + col * 36;  // A-row oc = col
    int4v WA[3];
    WA[0] = *(const int4v*)(wb + quad * 4);
    WA[1] = *(const int4v*)(wb + 16 + quad * 4);
    WA[2] = kq0 ? *(const int4v*)(wb + 32) : (int4v){0, 0, 0, 0};
    const int4v acc0 = (int4v){1, 1, 1, 1} - *(const int4v*)(wsd + 80 + quad * 4);
    const int8_t* a1b = (const int8_t*)smem;
    // incremental (oy,ox) over output pixel p = nt*16+col, nt += 4 (p += 64)
    const int p0 = wv * 16 + col;
    int oy = p0 / 24, ox = p0 - oy * 24;
    const int8_t* abase = a1b + (oy * 26 + ox) * 16;
    int* h2p = (int*)smem + 2704 + (oy * 25 + ox) * 4 + quad;
    for (int it = 0; it < 9; ++it) {
      int4v acc = acc0;
      acc = mfma_i8(WA[0], *(const int4v*)(abase + off2[0]), acc);
      acc = mfma_i8(WA[1], *(const int4v*)(abase + off2[1]), acc);
      acc = mfma_i8(WA[2], *(const int4v*)(abase + off2[2]), acc);
      *h2p = pack4(cl02(acc[0]), cl02(acc[1]), cl02(acc[2]), cl02(acc[3]));
      abase += 1088;  // a1: (oy+=2, ox+=16), stride 26
      h2p += 264;     // h2: (oy+=2, ox+=16), stride 25 (dwords)
      ox += 16;
      if (ox >= 24) { ox -= 24; abase += 32; h2p += 4; }
    }
  }
  __syncthreads();

  // Phase 3: conv3 + in-register pool. Pixels tiled pool-quad-major:
  // tile pt covers cells 4pt..4pt+3; lane col -> cell 4pt+(col>>2), sub col&3.
  // p4 (48 B/cell stride) is written into the a1 region (a1 dead).
  {
    int4v WA[2][3];
    int4v ac0[2];
#pragma unroll
    for (int ot = 0; ot < 2; ++ot) {
      const int* wb = wpack + 576 + (ot * 16 + col) * 36;
      WA[ot][0] = *(const int4v*)(wb + quad * 4);
      WA[ot][1] = *(const int4v*)(wb + 16 + quad * 4);
      WA[ot][2] = kq0 ? *(const int4v*)(wb + 32) : (int4v){0, 0, 0, 0};
      ac0[ot] = (int4v){1, 1, 1, 1} - *(const int4v*)(wsd + 96 + ot * 16 + quad * 4);
    }
    const int sub = col & 3;
    const int sy = sub >> 1, sx = sub & 1;
    const int cell0 = wv * 4 + (col >> 2);
    const int cy0 = cell0 / 11, cx0 = cell0 - cy0 * 11;
    const int aoff0 = ((cy0 * 2 + sy) * 25 + cx0 * 2 + sx) * 16;
    const int pb0 = cell0 * 12 + quad;
    const int aoffcap = ((20 + sy) * 25 + 20 + sx) * 16;  // cell 120 clamp
    const int pbcap = 120 * 12 + quad;
    const bool wlane = (sub == 0);
    const int8_t* h2b = (const int8_t*)(smem + 10816);
    int* p4 = (int*)smem;
    int aoff = aoff0, pb = pb0, cx = cx0;
    for (int pt = wv; pt < 31; pt += 4) {
      const int8_t* abase = h2b + ((aoff < aoffcap) ? aoff : aoffcap);
      const int pbu = (pb < pbcap) ? pb : pbcap;
      const int4v B0 = *(const int4v*)(abase + off3[0]);
      const int4v B1 = *(const int4v*)(abase + off3[1]);
      const int4v B2 = *(const int4v*)(abase + off3[2]);
#pragma unroll
      for (int ot = 0; ot < 2; ++ot) {
        int4v acc = ac0[ot];
        acc = mfma_i8(WA[ot][0], B0, acc);
        acc = mfma_i8(WA[ot][1], B1, acc);
        acc = mfma_i8(WA[ot][2], B2, acc);
        int s = pack4(cl02(acc[0]), cl02(acc[1]), cl02(acc[2]), cl02(acc[3]));
        // sum (s3+1) packed bytes across the lane nibble (cell's 2x2)
        s += __builtin_amdgcn_update_dpp(0, s, 0xB1, 0xF, 0xF, false);
        s += __builtin_amdgcn_update_dpp(0, s, 0x4E, 0xF, 0xF, false);
        if (wlane) p4[pbu + ot * 4] = s;
      }
      aoff += 960;  // cell += 16: (cy+=1, cx+=5), stride 25
      pb += 192;    // cell += 16, stride 12 dw
      cx += 5;
      if (cx >= 11) { cx -= 11; aoff += 448; }
    }
  }
  __syncthreads();

  // Phase 4: FC. acc = sum n*sw = 4*true + 4*rowsum(sw); badj corrects.
  // Mapping j=u%10, k=u/10: 10 lanes share each pos (LDS broadcast reads,
  // conflict-free with the 48 B cell stride); atomics 7-way per out_acc[j].
  if (tid < 250) {
    const int j = tid % 10, k = tid / 10;
    const int* p4d = (const int*)smem;
    int acc = 0;
    for (int pos = k; pos < 121; pos += 25) {
      const int4 pa = *(const int4*)(p4d + pos * 12);
      const int4 pb = *(const int4*)(p4d + pos * 12 + 4);
      const int* swr = sw + j * 968 + pos * 8;
      const int4 wa = *(const int4*)(swr);
      const int4 wbv = *(const int4*)(swr + 4);
      acc = dot4(pa.x, wa.x, acc);
      acc = dot4(pa.y, wa.y, acc);
      acc = dot4(pa.z, wa.z, acc);
      acc = dot4(pa.w, wa.w, acc);
      acc = dot4(pb.x, wbv.x, acc);
      acc = dot4(pb.y, wbv.y, acc);
      acc = dot4(pb.z, wbv.z, acc);
      acc = dot4(pb.w, wbv.w, acc);
    }
    atomicAdd(&out_acc[j], acc);
  }
  __syncthreads();
  if (tid < 10)
    out[(size_t)img * 10 + tid] = 0.25f * (float)out_acc[tid] + badj[tid];
}

extern "C" void kernel_launch(void* const* d_in, const int* in_sizes, int n_in,
                              void* d_out, int out_size, void* d_ws, size_t ws_size,
                              hipStream_t stream) {
  const float* x   = (const float*)d_in[0];
  const float* w1  = (const float*)d_in[1];
  const float* w2  = (const float*)d_in[2];
  const float* w3  = (const float*)d_in[3];
  const float* wfc = (const float*)d_in[4];
  const float* bfc = (const float*)d_in[5];
  float* out = (float*)d_out;
  int* wsd = (int*)d_ws;
  const int B = in_sizes[0] / 784;
  const int NMAX = (B + 1) / 2;

  hipLaunchKernelGGL(k_prep_max, dim3(NMAX + 56), dim3(256), 0, stream,
                     x, w1, w2, w3, wfc, bfc, wsd, B, NMAX);
  hipLaunchKernelGGL(k_forward, dim3(B), dim3(256), 0, stream, x, w1,
                     (const int*)wsd, out, B);
}